// Round 7
// baseline (138.754 us; speedup 1.0000x reference)
//
#include <hip/hip_runtime.h>
#include <math.h>

#define B_DIM 1024
#define D_DIM 512
#define H_DIM 128
#define S_DIM 511
#define PI_F 3.14159265358979323846f
#define ZSWZ_BYTES (16u * 1024u * 64u)   /* 1 MiB: [kt 16][row 1024][64B], swizzle-baked */
#define NT32_TOTAL 4336                   /* sum over s of ceil((s+1)/32) */
#define W1BF_BYTES ((size_t)NT32_TOTAL * 8192)
#define EPI_OFF 65536

typedef __attribute__((ext_vector_type(8))) short short8;
typedef __attribute__((ext_vector_type(4))) float f32x4;

#define GLDS16(src, dst)                                                        \
    __builtin_amdgcn_global_load_lds(                                           \
        (const __attribute__((address_space(1))) unsigned int*)(src),           \
        (__attribute__((address_space(3))) unsigned int*)(dst), 16, 0, 0)

static __device__ __forceinline__ unsigned cvt_pk_bf16(float lo, float hi) {
    unsigned r;
    asm("v_cvt_pk_bf16_f32 %0, %1, %2" : "=v"(r) : "v"(lo), "v"(hi));
    return r;
}

// 32-wide k-tiles before site s in the packed W1bf buffer:
// tb32(s) = sum_{K=1..s} ceil(K/32)
static __device__ __forceinline__ int tb32(int s) {
    const int q = s >> 5, r = s & 31;
    return 16 * q * (q + 1) + r * (q + 1);
}

// ---------------------------------------------------------------------------
// Pack kernel. Blocks [0,256): z f32 -> bf16 swizzled 64B rows.
//   z_swz[kt][row][slot g (16B)] holds source cols kt*32 + (g ^ ((row>>1)&3))*8 ..+8
// Blocks [256, 256+511*16): W1 f32 [k][h] -> bf16 [h][k] 8KB tiles (BK=32),
//   triangular-packed, K-mask baked in, same slot swizzle on h rows.
// ---------------------------------------------------------------------------
__global__ __launch_bounds__(256) void pack_kernel(
        const float* __restrict__ z, const float* __restrict__ W1,
        unsigned char* __restrict__ z_swz, unsigned char* __restrict__ w1bf)
{
    if (blockIdx.x < 256) {
        const int gid = blockIdx.x * 256 + threadIdx.x;   // 65536
        const int g   = gid & 3;
        const int row = (gid >> 2) & 1023;
        const int kt  = gid >> 12;                        // 0..15
        const int srcg = g ^ ((row >> 1) & 3);
        const float* src = z + (size_t)row * D_DIM + kt * 32 + srcg * 8;
        float4 a = *(const float4*)src;
        float4 b = *(const float4*)(src + 4);
        uint4 w;
        w.x = cvt_pk_bf16(a.x, a.y);
        w.y = cvt_pk_bf16(a.z, a.w);
        w.z = cvt_pk_bf16(b.x, b.y);
        w.w = cvt_pk_bf16(b.z, b.w);
        *(uint4*)(z_swz + (size_t)kt * 65536 + row * 64 + g * 16) = w;
        return;
    }
    const int tb = blockIdx.x - 256;          // 0..8175
    const int s  = tb >> 4;
    const int kk = tb & 15;
    if (s >= S_DIM || kk > (s >> 5)) return;  // valid kk < (s>>5)+1
    const int k0 = kk << 5;
    const int t  = threadIdx.x;
    const int h2 = t & 63;                    // h pair: 2*h2, 2*h2+1
    const int mw = t >> 6;                    // k-granule 0..3 (k = k0+mw*8..+7)
    const float* __restrict__ W1s = W1 + (size_t)s * (D_DIM * H_DIM);
    unsigned char* out = w1bf + (size_t)(tb32(s) + kk) * 8192;
    const int h0 = h2 * 2, h1 = h2 * 2 + 1;
    const int slot = mw ^ (h2 & 3);           // (h0>>1)&3 == (h1>>1)&3 == h2&3
    float2 v[8];
#pragma unroll
    for (int e = 0; e < 8; ++e) {
        const int gk = k0 + mw * 8 + e;
        v[e] = (gk <= s) ? *(const float2*)(W1s + (size_t)gk * H_DIM + h0)
                         : (float2){0.f, 0.f};
    }
    uint4 w0, w1;
    w0.x = cvt_pk_bf16(v[0].x, v[1].x); w0.y = cvt_pk_bf16(v[2].x, v[3].x);
    w0.z = cvt_pk_bf16(v[4].x, v[5].x); w0.w = cvt_pk_bf16(v[6].x, v[7].x);
    w1.x = cvt_pk_bf16(v[0].y, v[1].y); w1.y = cvt_pk_bf16(v[2].y, v[3].y);
    w1.z = cvt_pk_bf16(v[4].y, v[5].y); w1.w = cvt_pk_bf16(v[6].y, v[7].y);
    *(uint4*)(out + h0 * 64 + slot * 16) = w0;
    *(uint4*)(out + h1 * 64 + slot * 16) = w1;
}

// ---------------------------------------------------------------------------
// Chained site kernel (PRE=true): 512 blocks x 512 threads (8 waves),
// 2 blocks/CU (4 waves/SIMD). BK=32, 4-slot LDS ring (16KB/slot), prefetch
// depth 3, counted vmcnt (4/2/0), ONE barrier per step. Chain = 8 snake
// sites; chain c's 8 bblocks share XCD c&7.
// PRE=false: legacy one-site-per-block fallback (launch with 256 threads).
// ---------------------------------------------------------------------------
template<bool PRE>
__global__ __launch_bounds__(512, 4) void ar_site_kernel(
        const float* __restrict__ z, const unsigned char* __restrict__ z_swz,
        const unsigned char* __restrict__ w1bf,
        const float* __restrict__ W1, const float* __restrict__ b1,
        const float* __restrict__ W2, const float* __restrict__ b2,
        float* __restrict__ x_out, float* __restrict__ ld_out)
{
    __shared__ __align__(16) unsigned char lds[73728]; // ring 4x16KB + epi

    const int tid  = threadIdx.x;
    const int lane = tid & 63;
    const int wid  = tid >> 6;
    const int l15  = lane & 15;
    const int l16  = lane >> 4;

    if (PRE) {
        const int wr   = wid >> 2;              // 0..1 : rows wr*64..+63
        const int wc   = wid & 3;               // 0..3 : cols wc*32..+31
        const int ib   = blockIdx.x;            // 0..511
        const int c    = (((ib >> 3) & 7) << 3) | (ib & 7);  // chain 0..63
        const int bblk = ib >> 6;               // 0..7
        const int brow0 = bblk * 128;

        // ---- prefetch stream state over (t, kk) of this chain
        int pf_t = 0, pf_kk = 0, pf_step = 0;
        int pf_s = 510 - c;
        int pf_base = tb32(pf_s);

        auto pf_stage = [&]() {
            if (pf_t >= 8) return;
            unsigned char* slotp = lds + (pf_step & 3) * 16384;
            if (wid < 4) {
                const unsigned char* srcA = z_swz + (size_t)pf_kk * 65536
                    + (size_t)(brow0 + wid * 32) * 64 + lane * 16;
                unsigned char* dstA = slotp + wid * 2048;
                GLDS16(srcA, dstA);
                GLDS16(srcA + 1024, dstA + 1024);
            } else {
                const int w2 = wid - 4;
                const unsigned char* srcB = w1bf + (size_t)(pf_base + pf_kk) * 8192
                    + (size_t)(w2 * 32) * 64 + lane * 16;
                unsigned char* dstB = slotp + 8192 + w2 * 2048;
                GLDS16(srcB, dstB);
                GLDS16(srcB + 1024, dstB + 1024);
            }
            ++pf_step; ++pf_kk;
            if (pf_kk == (pf_s >> 5) + 1) {
                pf_kk = 0; ++pf_t;
                while (pf_t < 8) {
                    const int j = pf_t * 64 + ((pf_t & 1) ? (63 - c) : c);
                    if (j < S_DIM) { pf_s = 510 - j; pf_base = tb32(pf_s); break; }
                    ++pf_t;
                }
            }
        };

        int csteps = 0;
#pragma unroll
        for (int t = 0; t < 8; ++t) {
            const int j = t * 64 + ((t & 1) ? (63 - c) : c);
            if (j < S_DIM) csteps += ((510 - j) >> 5) + 1;
        }

        pf_stage(); pf_stage(); pf_stage();    // depth-3 prologue (6 loads/wave)

        int step = 0;
        float ld_acc = 0.f;

        for (int t = 0; t < 8; ++t) {
            const int j = t * 64 + ((t & 1) ? (63 - c) : c);
            if (j >= S_DIM) continue;
            const int s   = 510 - j;
            const int nt  = (s >> 5) + 1;
            const int idx = s + 1;

            f32x4 acc[4][2];
#pragma unroll
            for (int mi = 0; mi < 4; ++mi)
#pragma unroll
                for (int ni = 0; ni < 2; ++ni)
                    acc[mi][ni] = (f32x4){0.f, 0.f, 0.f, 0.f};

            for (int kk = 0; kk < nt; ++kk) {
                // own step-k loads landed when <= 2*(future staged steps) remain
                if (step + 2 < csteps)      asm volatile("s_waitcnt vmcnt(4)" ::: "memory");
                else if (step + 1 < csteps) asm volatile("s_waitcnt vmcnt(2)" ::: "memory");
                else                        asm volatile("s_waitcnt vmcnt(0)" ::: "memory");
                __builtin_amdgcn_s_barrier();       // all waves' loads landed
                __builtin_amdgcn_sched_barrier(0);
                pf_stage();                          // refill slot freed last step
                const unsigned char* bufp = lds + (step & 3) * 16384;
                short8 af[4], bfr[2];
#pragma unroll
                for (int ni = 0; ni < 2; ++ni) {
                    const int h = wc * 32 + ni * 16 + l15;
                    bfr[ni] = *(const short8*)(bufp + 8192 + h * 64
                                               + ((l16 * 16) ^ ((((h >> 1) & 3)) << 4)));
                }
#pragma unroll
                for (int mi = 0; mi < 4; ++mi) {
                    const int r = wr * 64 + mi * 16 + l15;
                    af[mi] = *(const short8*)(bufp + r * 64
                                              + ((l16 * 16) ^ ((((r >> 1) & 3)) << 4)));
                }
                __builtin_amdgcn_s_setprio(1);
#pragma unroll
                for (int mi = 0; mi < 4; ++mi)
#pragma unroll
                    for (int ni = 0; ni < 2; ++ni)
                        acc[mi][ni] = __builtin_amdgcn_mfma_f32_16x16x32_bf16(
                            af[mi], bfr[ni], acc[mi][ni], 0, 0, 0);
                __builtin_amdgcn_s_setprio(0);
                ++step;
            }

            // ---- site epilogue: p = relu(acc+b1) @ W2; NCP transform
            float b1v[2], w2a[2], w2b[2];
#pragma unroll
            for (int ni = 0; ni < 2; ++ni) {
                const int cc = wc * 32 + ni * 16 + l15;
                b1v[ni] = b1[(size_t)s * H_DIM + cc];
                const float2 w2v = *(const float2*)(W2 + ((size_t)s * H_DIM + cc) * 2);
                w2a[ni] = w2v.x;
                w2b[ni] = w2v.y;
            }
#pragma unroll
            for (int mi = 0; mi < 4; ++mi) {
                float p0[4], p1[4];
#pragma unroll
                for (int r = 0; r < 4; ++r) {
                    float a0 = 0.f, a1 = 0.f;
#pragma unroll
                    for (int ni = 0; ni < 2; ++ni) {
                        float h = fmaxf(acc[mi][ni][r] + b1v[ni], 0.f);
                        a0 = fmaf(h, w2a[ni], a0);
                        a1 = fmaf(h, w2b[ni], a1);
                    }
                    a0 += __shfl_xor(a0, 1); a0 += __shfl_xor(a0, 2);
                    a0 += __shfl_xor(a0, 4); a0 += __shfl_xor(a0, 8);
                    a1 += __shfl_xor(a1, 1); a1 += __shfl_xor(a1, 2);
                    a1 += __shfl_xor(a1, 4); a1 += __shfl_xor(a1, 8);
                    p0[r] = a0; p1[r] = a1;
                }
                if (l15 == 0) {
                    const int rowb = wr * 64 + mi * 16 + l16 * 4;
                    const int slot = (wc ^ (rowb >> 2)) & 3;
#pragma unroll
                    for (int r = 0; r < 4; ++r)
                        *(float2*)(lds + EPI_OFF + (rowb + r) * 32 + slot * 8)
                            = (float2){p0[r], p1[r]};
                }
            }
            asm volatile("s_waitcnt lgkmcnt(0)" ::: "memory");
            __builtin_amdgcn_s_barrier();
            __builtin_amdgcn_sched_barrier(0);
            if (tid < 128) {
                const int row = tid;
                float alpha = b2[(size_t)s * 2 + 0];
                float beta  = b2[(size_t)s * 2 + 1];
#pragma unroll
                for (int p = 0; p < 4; ++p) {
                    const float2 v = *(const float2*)(lds + EPI_OFF + row * 32 + p * 8);
                    alpha += v.x; beta += v.y;
                }
                const int grow = brow0 + row;
                const float phi = z[(size_t)grow * D_DIM + idx];
                const float u = tanf(0.5f * (phi - PI_F));
                const float a = expf(alpha);
                const float v = fmaf(a, u, beta);
                x_out[(size_t)grow * D_DIM + idx] = 2.0f * atanf(v) + PI_F;
                ld_acc += alpha + log1pf(u * u) - log1pf(v * v);
            }
        }
        if (tid < 128) atomicAdd(ld_out + brow0 + tid, ld_acc);
        if (c == 0 && tid < 128)
            x_out[(size_t)(brow0 + tid) * D_DIM] = z[(size_t)(brow0 + tid) * D_DIM];
        return;
    }

    // ---------------- legacy fallback (launched with 256 threads) ----------
    const int wr2 = wid >> 1, wc2 = wid & 1;
    const int ib    = blockIdx.x;
    const int s_idx = ((ib >> 6) << 3) | (ib & 7);
    if (s_idx >= S_DIM) return;
    const int s     = S_DIM - 1 - s_idx;
    const int bblk  = (ib >> 3) & 7;
    const int brow0 = bblk * 128;
    const int K     = s + 1;
    const int idx   = s + 1;
    const float* __restrict__ W1s = W1 + (size_t)s * (D_DIM * H_DIM);

    f32x4 acc[4][4];
#pragma unroll
    for (int mi = 0; mi < 4; ++mi)
#pragma unroll
        for (int ni = 0; ni < 4; ++ni)
            acc[mi][ni] = (f32x4){0.f, 0.f, 0.f, 0.f};

    const int ntiles = (K + 63) >> 6;
    for (int kk = 0; kk < ntiles; ++kk) {
        const int k0 = kk << 6;
        const int g  = tid & 7;
        const int rb = tid >> 3;
#pragma unroll
        for (int p = 0; p < 4; ++p) {
            const int row  = p * 32 + rb;
            const int srcg = g ^ (row & 7);
            const float* zp = z + (size_t)(brow0 + row) * D_DIM + k0 + srcg * 8;
            float4 va = *(const float4*)zp;
            float4 vb = *(const float4*)(zp + 4);
            uint4 w;
            w.x = cvt_pk_bf16(va.x, va.y);
            w.y = cvt_pk_bf16(va.z, va.w);
            w.z = cvt_pk_bf16(vb.x, vb.y);
            w.w = cvt_pk_bf16(vb.z, vb.w);
            *(uint4*)(lds + row * 128 + g * 16) = w;
        }
        const int hgrp  = tid & 31;
        const int kgrp  = tid >> 5;
        const int kbase = k0 + kgrp * 8;
        const float* wp = W1s + (size_t)kbase * H_DIM + hgrp * 4;
        float4 cc[8];
#pragma unroll
        for (int jj = 0; jj < 8; ++jj) {
            float4 v = *(const float4*)(wp + (size_t)jj * H_DIM);
            const bool ok = (kbase + jj) < K;
            v.x = ok ? v.x : 0.f;  v.y = ok ? v.y : 0.f;
            v.z = ok ? v.z : 0.f;  v.w = ok ? v.w : 0.f;
            cc[jj] = v;
        }
        const float* cf = (const float*)cc;
#pragma unroll
        for (int i2 = 0; i2 < 4; ++i2) {
            const int h = hgrp * 4 + i2;
            uint4 w;
            w.x = cvt_pk_bf16(cf[0 * 4 + i2], cf[1 * 4 + i2]);
            w.y = cvt_pk_bf16(cf[2 * 4 + i2], cf[3 * 4 + i2]);
            w.z = cvt_pk_bf16(cf[4 * 4 + i2], cf[5 * 4 + i2]);
            w.w = cvt_pk_bf16(cf[6 * 4 + i2], cf[7 * 4 + i2]);
            *(uint4*)(lds + 16384 + h * 128 + ((kgrp * 16) ^ ((h & 7) << 4))) = w;
        }
        __syncthreads();
#pragma unroll
        for (int ks = 0; ks < 2; ++ks) {
            const int kb = ks * 64 + l16 * 16;
            short8 af[4], bfr[4];
#pragma unroll
            for (int mi = 0; mi < 4; ++mi) {
                const int r = wr2 * 64 + mi * 16 + l15;
                af[mi] = *(const short8*)(lds + r * 128 + (kb ^ ((r & 7) << 4)));
            }
#pragma unroll
            for (int ni = 0; ni < 4; ++ni) {
                const int h = wc2 * 64 + ni * 16 + l15;
                bfr[ni] = *(const short8*)(lds + 16384 + h * 128 + (kb ^ ((h & 7) << 4)));
            }
#pragma unroll
            for (int mi = 0; mi < 4; ++mi)
#pragma unroll
                for (int ni = 0; ni < 4; ++ni)
                    acc[mi][ni] = __builtin_amdgcn_mfma_f32_16x16x32_bf16(
                        af[mi], bfr[ni], acc[mi][ni], 0, 0, 0);
        }
        __syncthreads();
    }

    float b1v[4], w2a[4], w2b[4];
#pragma unroll
    for (int ni = 0; ni < 4; ++ni) {
        const int cc2 = wc2 * 64 + ni * 16 + l15;
        b1v[ni] = b1[(size_t)s * H_DIM + cc2];
        const float* w2p = W2 + ((size_t)s * H_DIM + cc2) * 2;
        w2a[ni] = w2p[0];
        w2b[ni] = w2p[1];
    }
    float p0s[4][4], p1s[4][4];
#pragma unroll
    for (int mi = 0; mi < 4; ++mi)
#pragma unroll
        for (int r = 0; r < 4; ++r) {
            float p0 = 0.f, p1 = 0.f;
#pragma unroll
            for (int ni = 0; ni < 4; ++ni) {
                float h = acc[mi][ni][r] + b1v[ni];
                h = fmaxf(h, 0.f);
                p0 = fmaf(h, w2a[ni], p0);
                p1 = fmaf(h, w2b[ni], p1);
            }
            p0s[mi][r] = p0; p1s[mi][r] = p1;
        }
#pragma unroll
    for (int mi = 0; mi < 4; ++mi)
#pragma unroll
        for (int r = 0; r < 4; ++r) {
            p0s[mi][r] += __shfl_xor(p0s[mi][r], 1);
            p0s[mi][r] += __shfl_xor(p0s[mi][r], 2);
            p1s[mi][r] += __shfl_xor(p1s[mi][r], 1);
            p1s[mi][r] += __shfl_xor(p1s[mi][r], 2);
        }
    if ((lane & 3) == 0) {
        const int cw = wc2 * 4 + (l15 >> 2);
#pragma unroll
        for (int mi = 0; mi < 4; ++mi)
#pragma unroll
            for (int r = 0; r < 4; ++r) {
                const int row = wr2 * 64 + mi * 16 + l16 * 4 + r;
                *(float2*)(lds + EPI_OFF + (row * 8 + (cw ^ (row & 7))) * 8)
                    = (float2){p0s[mi][r], p1s[mi][r]};
            }
    }
    __syncthreads();
    if (tid < 128) {
        const int row = tid;
        float alpha = b2[(size_t)s * 2 + 0];
        float beta  = b2[(size_t)s * 2 + 1];
#pragma unroll
        for (int cw = 0; cw < 8; ++cw) {
            const float2 v = *(const float2*)(lds + EPI_OFF + (row * 8 + (cw ^ (row & 7))) * 8);
            alpha += v.x; beta += v.y;
        }
        const int grow = brow0 + row;
        const float phi = z[(size_t)grow * D_DIM + idx];
        const float u = tanf(0.5f * (phi - PI_F));
        const float a = expf(alpha);
        const float v = fmaf(a, u, beta);
        x_out[(size_t)grow * D_DIM + idx] = 2.0f * atanf(v) + PI_F;
        atomicAdd(ld_out + grow, alpha + log1pf(u * u) - log1pf(v * v));
        if (s_idx == 0)
            x_out[(size_t)grow * D_DIM] = z[(size_t)grow * D_DIM];
    }
}

extern "C" void kernel_launch(void* const* d_in, const int* in_sizes, int n_in,
                              void* d_out, int out_size, void* d_ws, size_t ws_size,
                              hipStream_t stream) {
    const float* z  = (const float*)d_in[0];
    const float* W1 = (const float*)d_in[1];
    const float* b1 = (const float*)d_in[2];
    const float* W2 = (const float*)d_in[3];
    const float* b2 = (const float*)d_in[4];
    float* x_out  = (float*)d_out;
    float* ld_out = x_out + (size_t)B_DIM * D_DIM;

    unsigned char* z_swz = (unsigned char*)d_ws;
    unsigned char* w1bf  = z_swz + ZSWZ_BYTES;
    const size_t need = ZSWZ_BYTES + W1BF_BYTES;

    hipMemsetAsync(ld_out, 0, B_DIM * sizeof(float), stream);
    if (ws_size >= need) {
        pack_kernel<<<dim3(256 + 511 * 16), dim3(256), 0, stream>>>(z, W1, z_swz, w1bf);
        ar_site_kernel<true><<<dim3(512), dim3(512), 0, stream>>>(
            z, z_swz, w1bf, W1, b1, W2, b2, x_out, ld_out);
    } else {
        ar_site_kernel<false><<<dim3(4096), dim3(256), 0, stream>>>(
            z, nullptr, nullptr, W1, b1, W2, b2, x_out, ld_out);
    }
}

// Round 8
// 107.053 us; speedup vs baseline: 1.2961x; 1.2961x over previous
//
#include <hip/hip_runtime.h>
#include <math.h>

#define B_DIM 1024
#define D_DIM 512
#define H_DIM 128
#define S_DIM 511
#define PI_F 3.14159265358979323846f
#define ZSWZ_BYTES (8u * 1024u * 128u)      /* 1 MiB: z bf16, swizzle-baked */
#define NTILES_TOTAL 2296                    /* sum over s of ceil((s+1)/64) */
#define W1BF_BYTES ((size_t)NTILES_TOTAL * 16384)
#define EPI_OFF 65536

typedef __attribute__((ext_vector_type(8))) short short8;
typedef __attribute__((ext_vector_type(4))) float f32x4;

#define GLDS16(src, dst)                                                        \
    __builtin_amdgcn_global_load_lds(                                           \
        (const __attribute__((address_space(1))) unsigned int*)(src),           \
        (__attribute__((address_space(3))) unsigned int*)(dst), 16, 0, 0)

static __device__ __forceinline__ unsigned cvt_pk_bf16(float lo, float hi) {
    unsigned r;
    asm("v_cvt_pk_bf16_f32 %0, %1, %2" : "=v"(r) : "v"(lo), "v"(hi));
    return r;
}

// 64-wide k-tiles before site s in the packed W1bf buffer
static __device__ __forceinline__ int tiles_before(int s) {
    const int q = s >> 6, r = s & 63;
    return s + 32 * q * (q - 1) + q * r;
}

// ---------------------------------------------------------------------------
// Pack kernel (verified R3-R5). Blocks [0,256): z f32 -> bf16 swizzled tiles.
// Blocks [256,...): W1 f32 [k][h] -> bf16 [h][k] swizzled 16KB tiles (BK=64),
// triangular-packed, K-mask baked in.
// ---------------------------------------------------------------------------
__global__ __launch_bounds__(256) void pack_kernel(
        const float* __restrict__ z, const float* __restrict__ W1,
        unsigned char* __restrict__ z_swz, unsigned char* __restrict__ w1bf)
{
    if (blockIdx.x < 256) {
        const int gid = blockIdx.x * 256 + threadIdx.x;   // 65536 threads
        const int g   = gid & 7;
        const int row = (gid >> 3) & 1023;
        const int kt  = gid >> 13;
        const int srcg = g ^ (row & 7);
        const float* src = z + (size_t)row * D_DIM + kt * 64 + srcg * 8;
        float4 a = *(const float4*)src;
        float4 b = *(const float4*)(src + 4);
        uint4 w;
        w.x = cvt_pk_bf16(a.x, a.y);
        w.y = cvt_pk_bf16(a.z, a.w);
        w.z = cvt_pk_bf16(b.x, b.y);
        w.w = cvt_pk_bf16(b.z, b.w);
        *(uint4*)(z_swz + (size_t)kt * 131072 + row * 128 + g * 16) = w;
        return;
    }
    const int tb = blockIdx.x - 256;          // 0..4087
    const int s  = tb >> 3;
    const int kk = tb & 7;
    if (s >= S_DIM || kk > (s >> 6)) return;
    const int k0 = kk << 6;
    const int t  = threadIdx.x;
    const int h2 = t & 63;
    const int mw = t >> 6;
    const float* __restrict__ W1s = W1 + (size_t)s * (D_DIM * H_DIM);
    unsigned char* out = w1bf + (size_t)(tiles_before(s) + kk) * 16384;
    const int h0 = h2 * 2, h1 = h2 * 2 + 1;
#pragma unroll
    for (int half = 0; half < 2; ++half) {
        const int m = mw + half * 4;
        float2 v[8];
#pragma unroll
        for (int e = 0; e < 8; ++e) {
            const int gk = k0 + m * 8 + e;
            v[e] = (gk <= s) ? *(const float2*)(W1s + (size_t)gk * H_DIM + h0)
                             : (float2){0.f, 0.f};
        }
        uint4 w0, w1;
        w0.x = cvt_pk_bf16(v[0].x, v[1].x); w0.y = cvt_pk_bf16(v[2].x, v[3].x);
        w0.z = cvt_pk_bf16(v[4].x, v[5].x); w0.w = cvt_pk_bf16(v[6].x, v[7].x);
        w1.x = cvt_pk_bf16(v[0].y, v[1].y); w1.y = cvt_pk_bf16(v[2].y, v[3].y);
        w1.z = cvt_pk_bf16(v[4].y, v[5].y); w1.w = cvt_pk_bf16(v[6].y, v[7].y);
        *(uint4*)(out + h0 * 128 + ((m ^ (h0 & 7)) << 4)) = w0;
        *(uint4*)(out + h1 * 128 + ((m ^ (h1 & 7)) << 4)) = w1;
    }
}

// ---------------------------------------------------------------------------
// Chained site kernel (PRE=true): 512 blocks = 64 chains x 8 bblocks,
// 2 blocks/CU. BK=64, 2-slot ring. NEW schedule: ONE barrier per step,
// stage(k+1) issued at TOP of body k (full-step flight time before its
// vmcnt(0) drain), ds_read/MFMA interleaved so LDS and MFMA pipes overlap.
// ---------------------------------------------------------------------------
template<bool PRE>
__global__ __launch_bounds__(256, 2) void ar_site_kernel(
        const float* __restrict__ z, const unsigned char* __restrict__ z_swz,
        const unsigned char* __restrict__ w1bf,
        const float* __restrict__ W1, const float* __restrict__ b1,
        const float* __restrict__ W2, const float* __restrict__ b2,
        float* __restrict__ x_out, float* __restrict__ ld_out)
{
    __shared__ __align__(16) unsigned char lds[73728]; // ring 2x32KB + epi 8KB

    const int tid  = threadIdx.x;
    const int lane = tid & 63;
    const int wid  = tid >> 6;
    const int wr   = wid >> 1;
    const int wc   = wid & 1;
    const int l15  = lane & 15;
    const int l16  = lane >> 4;

    if (PRE) {
        const int ib   = blockIdx.x;            // 0..511
        const int c    = (((ib >> 3) & 7) << 3) | (ib & 7);  // chain 0..63
        const int bblk = ib >> 6;               // 0..7
        const int brow0 = bblk * 128;

        // ---- prefetch stream state over (t, kk) of this chain
        int pf_t = 0, pf_kk = 0, pf_step = 0;
        int pf_s = 510 - c;
        int pf_base = tiles_before(pf_s);

        auto pf_stage = [&]() {
            if (pf_t >= 8) return;
            const int slot = pf_step & 1;
            const unsigned char* srcA = z_swz + (size_t)pf_kk * 131072
                                        + (size_t)brow0 * 128 + wid * 4096 + lane * 16;
            const unsigned char* srcB = w1bf + (size_t)(pf_base + pf_kk) * 16384
                                        + wid * 4096 + lane * 16;
            unsigned char* dstA = lds + slot * 32768 + wid * 4096;
            unsigned char* dstB = lds + slot * 32768 + 16384 + wid * 4096;
#pragma unroll
            for (int i2 = 0; i2 < 4; ++i2) {
                GLDS16(srcA + i2 * 1024, dstA + i2 * 1024);
                GLDS16(srcB + i2 * 1024, dstB + i2 * 1024);
            }
            ++pf_step; ++pf_kk;
            if (pf_kk == ((pf_s >> 6) + 1)) {
                pf_kk = 0; ++pf_t;
                while (pf_t < 8) {
                    const int j = pf_t * 64 + ((pf_t & 1) ? (63 - c) : c);
                    if (j < S_DIM) { pf_s = 510 - j; pf_base = tiles_before(pf_s); break; }
                    ++pf_t;
                }
            }
        };

        pf_stage();                    // depth-1 prologue: step 0 -> slot 0

        int step = 0;
        float ld_acc = 0.f;

        for (int t = 0; t < 8; ++t) {
            const int j = t * 64 + ((t & 1) ? (63 - c) : c);
            if (j >= S_DIM) continue;
            const int s   = 510 - j;
            const int nt  = (s >> 6) + 1;
            const int idx = s + 1;

            f32x4 acc[4][4];
#pragma unroll
            for (int mi = 0; mi < 4; ++mi)
#pragma unroll
                for (int ni = 0; ni < 4; ++ni)
                    acc[mi][ni] = (f32x4){0.f, 0.f, 0.f, 0.f};

            for (int kk = 0; kk < nt; ++kk) {
                // step k's loads (issued at top of body k-1) — short drain
                asm volatile("s_waitcnt vmcnt(0)" ::: "memory");
                __builtin_amdgcn_s_barrier();
                __builtin_amdgcn_sched_barrier(0);
                const unsigned char* bufp = lds + (step & 1) * 32768;

                pf_stage();                          // stage step k+1 EARLY

                // ---- ks=0: ds_read + MFMA
                short8 af0[4], bf0[4], af1[4], bf1[4];
                {
                    const int kb = l16 * 16;
#pragma unroll
                    for (int mi = 0; mi < 4; ++mi) {
                        const int r = wr * 64 + mi * 16 + l15;
                        af0[mi] = *(const short8*)(bufp + r * 128 + (kb ^ ((r & 7) << 4)));
                    }
#pragma unroll
                    for (int ni = 0; ni < 4; ++ni) {
                        const int h = wc * 64 + ni * 16 + l15;
                        bf0[ni] = *(const short8*)(bufp + 16384 + h * 128 + (kb ^ ((h & 7) << 4)));
                    }
                }
                __builtin_amdgcn_s_setprio(1);
#pragma unroll
                for (int mi = 0; mi < 4; ++mi)
#pragma unroll
                    for (int ni = 0; ni < 4; ++ni)
                        acc[mi][ni] = __builtin_amdgcn_mfma_f32_16x16x32_bf16(
                            af0[mi], bf0[ni], acc[mi][ni], 0, 0, 0);
                __builtin_amdgcn_s_setprio(0);

                // ---- ks=1: ds_read + MFMA (compiler overlaps with ks0 MFMA)
                {
                    const int kb = 64 + l16 * 16;
#pragma unroll
                    for (int mi = 0; mi < 4; ++mi) {
                        const int r = wr * 64 + mi * 16 + l15;
                        af1[mi] = *(const short8*)(bufp + r * 128 + (kb ^ ((r & 7) << 4)));
                    }
#pragma unroll
                    for (int ni = 0; ni < 4; ++ni) {
                        const int h = wc * 64 + ni * 16 + l15;
                        bf1[ni] = *(const short8*)(bufp + 16384 + h * 128 + (kb ^ ((h & 7) << 4)));
                    }
                }
                __builtin_amdgcn_s_setprio(1);
#pragma unroll
                for (int mi = 0; mi < 4; ++mi)
#pragma unroll
                    for (int ni = 0; ni < 4; ++ni)
                        acc[mi][ni] = __builtin_amdgcn_mfma_f32_16x16x32_bf16(
                            af1[mi], bf1[ni], acc[mi][ni], 0, 0, 0);
                __builtin_amdgcn_s_setprio(0);
                ++step;
            }

            // ---- site epilogue: p = relu(acc+b1) @ W2, then NCP transform
            float b1v[4], w2a[4], w2b[4];
#pragma unroll
            for (int ni = 0; ni < 4; ++ni) {
                const int cc = wc * 64 + ni * 16 + l15;
                b1v[ni] = b1[(size_t)s * H_DIM + cc];
                const float2 w2v = *(const float2*)(W2 + ((size_t)s * H_DIM + cc) * 2);
                w2a[ni] = w2v.x;
                w2b[ni] = w2v.y;
            }
            float p0s[4][4], p1s[4][4];
#pragma unroll
            for (int mi = 0; mi < 4; ++mi)
#pragma unroll
                for (int r = 0; r < 4; ++r) {
                    float p0 = 0.f, p1 = 0.f;
#pragma unroll
                    for (int ni = 0; ni < 4; ++ni) {
                        float h = acc[mi][ni][r] + b1v[ni];
                        h = fmaxf(h, 0.f);
                        p0 = fmaf(h, w2a[ni], p0);
                        p1 = fmaf(h, w2b[ni], p1);
                    }
                    p0s[mi][r] = p0; p1s[mi][r] = p1;
                }
#pragma unroll
            for (int mi = 0; mi < 4; ++mi)
#pragma unroll
                for (int r = 0; r < 4; ++r) {
                    p0s[mi][r] += __shfl_xor(p0s[mi][r], 1);
                    p0s[mi][r] += __shfl_xor(p0s[mi][r], 2);
                    p1s[mi][r] += __shfl_xor(p1s[mi][r], 1);
                    p1s[mi][r] += __shfl_xor(p1s[mi][r], 2);
                }
            if ((lane & 3) == 0) {
                const int cw = wc * 4 + (l15 >> 2);
#pragma unroll
                for (int mi = 0; mi < 4; ++mi)
#pragma unroll
                    for (int r = 0; r < 4; ++r) {
                        const int row = wr * 64 + mi * 16 + l16 * 4 + r;
                        *(float2*)(lds + EPI_OFF + (row * 8 + (cw ^ (row & 7))) * 8)
                            = (float2){p0s[mi][r], p1s[mi][r]};
                    }
            }
            asm volatile("s_waitcnt lgkmcnt(0)" ::: "memory");
            __builtin_amdgcn_s_barrier();
            __builtin_amdgcn_sched_barrier(0);
            if (tid < 128) {
                const int row = tid;
                float alpha = b2[(size_t)s * 2 + 0];
                float beta  = b2[(size_t)s * 2 + 1];
#pragma unroll
                for (int cw = 0; cw < 8; ++cw) {
                    const float2 v = *(const float2*)(lds + EPI_OFF + (row * 8 + (cw ^ (row & 7))) * 8);
                    alpha += v.x; beta += v.y;
                }
                const int grow = brow0 + row;
                const float phi = z[(size_t)grow * D_DIM + idx];
                const float u = tanf(0.5f * (phi - PI_F));
                const float a = expf(alpha);
                const float v = fmaf(a, u, beta);
                x_out[(size_t)grow * D_DIM + idx] = 2.0f * atanf(v) + PI_F;
                ld_acc += alpha + log1pf(u * u) - log1pf(v * v);
            }
        }
        if (tid < 128) atomicAdd(ld_out + brow0 + tid, ld_acc);
        if (c == 0 && tid < 128)
            x_out[(size_t)(brow0 + tid) * D_DIM] = z[(size_t)(brow0 + tid) * D_DIM];
        return;
    }

    // ---------------- legacy fallback: one site per block, in-kernel cvt ----
    const int ib    = blockIdx.x;
    const int s_idx = ((ib >> 6) << 3) | (ib & 7);
    if (s_idx >= S_DIM) return;
    const int s     = S_DIM - 1 - s_idx;
    const int bblk  = (ib >> 3) & 7;
    const int brow0 = bblk * 128;
    const int K     = s + 1;
    const int idx   = s + 1;
    const float* __restrict__ W1s = W1 + (size_t)s * (D_DIM * H_DIM);

    f32x4 acc[4][4];
#pragma unroll
    for (int mi = 0; mi < 4; ++mi)
#pragma unroll
        for (int ni = 0; ni < 4; ++ni)
            acc[mi][ni] = (f32x4){0.f, 0.f, 0.f, 0.f};

    const int ntiles = (K + 63) >> 6;
    for (int kk = 0; kk < ntiles; ++kk) {
        const int k0 = kk << 6;
        const int g  = tid & 7;
        const int rb = tid >> 3;
#pragma unroll
        for (int p = 0; p < 4; ++p) {
            const int row  = p * 32 + rb;
            const int srcg = g ^ (row & 7);
            const float* zp = z + (size_t)(brow0 + row) * D_DIM + k0 + srcg * 8;
            float4 va = *(const float4*)zp;
            float4 vb = *(const float4*)(zp + 4);
            uint4 w;
            w.x = cvt_pk_bf16(va.x, va.y);
            w.y = cvt_pk_bf16(va.z, va.w);
            w.z = cvt_pk_bf16(vb.x, vb.y);
            w.w = cvt_pk_bf16(vb.z, vb.w);
            *(uint4*)(lds + row * 128 + g * 16) = w;
        }
        const int hgrp  = tid & 31;
        const int kgrp  = tid >> 5;
        const int kbase = k0 + kgrp * 8;
        const float* wp = W1s + (size_t)kbase * H_DIM + hgrp * 4;
        float4 cc[8];
#pragma unroll
        for (int jj = 0; jj < 8; ++jj) {
            float4 v = *(const float4*)(wp + (size_t)jj * H_DIM);
            const bool ok = (kbase + jj) < K;
            v.x = ok ? v.x : 0.f;  v.y = ok ? v.y : 0.f;
            v.z = ok ? v.z : 0.f;  v.w = ok ? v.w : 0.f;
            cc[jj] = v;
        }
        const float* cf = (const float*)cc;
#pragma unroll
        for (int i2 = 0; i2 < 4; ++i2) {
            const int h = hgrp * 4 + i2;
            uint4 w;
            w.x = cvt_pk_bf16(cf[0 * 4 + i2], cf[1 * 4 + i2]);
            w.y = cvt_pk_bf16(cf[2 * 4 + i2], cf[3 * 4 + i2]);
            w.z = cvt_pk_bf16(cf[4 * 4 + i2], cf[5 * 4 + i2]);
            w.w = cvt_pk_bf16(cf[6 * 4 + i2], cf[7 * 4 + i2]);
            *(uint4*)(lds + 16384 + h * 128 + ((kgrp * 16) ^ ((h & 7) << 4))) = w;
        }
        __syncthreads();
#pragma unroll
        for (int ks = 0; ks < 2; ++ks) {
            const int kb = ks * 64 + l16 * 16;
            short8 af[4], bfr[4];
#pragma unroll
            for (int mi = 0; mi < 4; ++mi) {
                const int r = wr * 64 + mi * 16 + l15;
                af[mi] = *(const short8*)(lds + r * 128 + (kb ^ ((r & 7) << 4)));
            }
#pragma unroll
            for (int ni = 0; ni < 4; ++ni) {
                const int h = wc * 64 + ni * 16 + l15;
                bfr[ni] = *(const short8*)(lds + 16384 + h * 128 + (kb ^ ((h & 7) << 4)));
            }
#pragma unroll
            for (int mi = 0; mi < 4; ++mi)
#pragma unroll
                for (int ni = 0; ni < 4; ++ni)
                    acc[mi][ni] = __builtin_amdgcn_mfma_f32_16x16x32_bf16(
                        af[mi], bfr[ni], acc[mi][ni], 0, 0, 0);
        }
        __syncthreads();
    }

    float b1v[4], w2a[4], w2b[4];
#pragma unroll
    for (int ni = 0; ni < 4; ++ni) {
        const int cc2 = wc * 64 + ni * 16 + l15;
        b1v[ni] = b1[(size_t)s * H_DIM + cc2];
        const float* w2p = W2 + ((size_t)s * H_DIM + cc2) * 2;
        w2a[ni] = w2p[0];
        w2b[ni] = w2p[1];
    }
    float p0s[4][4], p1s[4][4];
#pragma unroll
    for (int mi = 0; mi < 4; ++mi)
#pragma unroll
        for (int r = 0; r < 4; ++r) {
            float p0 = 0.f, p1 = 0.f;
#pragma unroll
            for (int ni = 0; ni < 4; ++ni) {
                float h = acc[mi][ni][r] + b1v[ni];
                h = fmaxf(h, 0.f);
                p0 = fmaf(h, w2a[ni], p0);
                p1 = fmaf(h, w2b[ni], p1);
            }
            p0s[mi][r] = p0; p1s[mi][r] = p1;
        }
#pragma unroll
    for (int mi = 0; mi < 4; ++mi)
#pragma unroll
        for (int r = 0; r < 4; ++r) {
            p0s[mi][r] += __shfl_xor(p0s[mi][r], 1);
            p0s[mi][r] += __shfl_xor(p0s[mi][r], 2);
            p1s[mi][r] += __shfl_xor(p1s[mi][r], 1);
            p1s[mi][r] += __shfl_xor(p1s[mi][r], 2);
        }
    if ((lane & 3) == 0) {
        const int cw = wc * 4 + (l15 >> 2);
#pragma unroll
        for (int mi = 0; mi < 4; ++mi)
#pragma unroll
            for (int r = 0; r < 4; ++r) {
                const int row = wr * 64 + mi * 16 + l16 * 4 + r;
                *(float2*)(lds + EPI_OFF + (row * 8 + (cw ^ (row & 7))) * 8)
                    = (float2){p0s[mi][r], p1s[mi][r]};
            }
    }
    __syncthreads();
    if (tid < 128) {
        const int row = tid;
        float alpha = b2[(size_t)s * 2 + 0];
        float beta  = b2[(size_t)s * 2 + 1];
#pragma unroll
        for (int cw = 0; cw < 8; ++cw) {
            const float2 v = *(const float2*)(lds + EPI_OFF + (row * 8 + (cw ^ (row & 7))) * 8);
            alpha += v.x; beta += v.y;
        }
        const int grow = brow0 + row;
        const float phi = z[(size_t)grow * D_DIM + idx];
        const float u = tanf(0.5f * (phi - PI_F));
        const float a = expf(alpha);
        const float v = fmaf(a, u, beta);
        x_out[(size_t)grow * D_DIM + idx] = 2.0f * atanf(v) + PI_F;
        atomicAdd(ld_out + grow, alpha + log1pf(u * u) - log1pf(v * v));
        if (s_idx == 0)
            x_out[(size_t)grow * D_DIM] = z[(size_t)grow * D_DIM];
    }
}

extern "C" void kernel_launch(void* const* d_in, const int* in_sizes, int n_in,
                              void* d_out, int out_size, void* d_ws, size_t ws_size,
                              hipStream_t stream) {
    const float* z  = (const float*)d_in[0];
    const float* W1 = (const float*)d_in[1];
    const float* b1 = (const float*)d_in[2];
    const float* W2 = (const float*)d_in[3];
    const float* b2 = (const float*)d_in[4];
    float* x_out  = (float*)d_out;
    float* ld_out = x_out + (size_t)B_DIM * D_DIM;

    unsigned char* z_swz = (unsigned char*)d_ws;
    unsigned char* w1bf  = z_swz + ZSWZ_BYTES;
    const size_t need = ZSWZ_BYTES + W1BF_BYTES;

    hipMemsetAsync(ld_out, 0, B_DIM * sizeof(float), stream);
    if (ws_size >= need) {
        pack_kernel<<<dim3(256 + 4088), dim3(256), 0, stream>>>(z, W1, z_swz, w1bf);
        ar_site_kernel<true><<<dim3(512), dim3(256), 0, stream>>>(
            z, z_swz, w1bf, W1, b1, W2, b2, x_out, ld_out);
    } else {
        ar_site_kernel<false><<<dim3(4096), dim3(256), 0, stream>>>(
            z, nullptr, nullptr, W1, b1, W2, b2, x_out, ld_out);
    }
}